// Round 16
// baseline (167.050 us; speedup 1.0000x reference)
//
#include <hip/hip_runtime.h>
#include <stdint.h>

#define SEQ    512
#define BATCH  1024
#define NTAG   54
#define TSTART 52
#define TSTOP  53
#define EMROW  (BATCH * NTAG)   // 55296 floats per timestep

// ---------------------------------------------------------------------------
// Linear-space CRF forward, time-split halves (r15) + hand-scheduled asm
// matvec (r16). wave0: u_{s+1}=(E u_s).ef_s forward; wave1: v_s=E^T(ef_s.v)
// backward; combine <u,v>. Rescale by power-of-2 via lagged exponent of
// lane 0. Ring-staged emissions (global_load_lds, 16 ahead, vmcnt(8)/group).
//
// r16 change: the 54x(readlane+fma) is 7 inline-asm blocks with E as "v"
// operands (defeats AGPR homing: r12-r15 showed ~225 issued instr/step vs
// ~130 written with VGPR_Count stuck at 68 => ~54 v_accvgpr_read per step),
// readlane->fmac distance 8 (no wait states), alternating accumulators.
// g-loop de-unrolled: 64-step bodies were ~60KB, blowing I-cache.
// ---------------------------------------------------------------------------

typedef const __attribute__((address_space(1))) void* gld_gptr;
typedef __attribute__((address_space(3))) void*       gld_lptr;

__device__ __forceinline__ void stage4(const float* g, float* l) {
    __builtin_amdgcn_global_load_lds((gld_gptr)g, (gld_lptr)l, 4, 0, 0);
}

#define BLK8(B, AA, AB)                                                       \
  do {                                                                        \
    int t0_,t1_,t2_,t3_,t4_,t5_,t6_,t7_;                                      \
    asm("v_readlane_b32 %[t0], %[uu], %[l0]\n\t"                              \
        "v_readlane_b32 %[t1], %[uu], %[l1]\n\t"                              \
        "v_readlane_b32 %[t2], %[uu], %[l2]\n\t"                              \
        "v_readlane_b32 %[t3], %[uu], %[l3]\n\t"                              \
        "v_readlane_b32 %[t4], %[uu], %[l4]\n\t"                              \
        "v_readlane_b32 %[t5], %[uu], %[l5]\n\t"                              \
        "v_readlane_b32 %[t6], %[uu], %[l6]\n\t"                              \
        "v_readlane_b32 %[t7], %[uu], %[l7]\n\t"                              \
        "v_fmac_f32 %[aa], %[t0], %[e0]\n\t"                                  \
        "v_fmac_f32 %[ab], %[t1], %[e1]\n\t"                                  \
        "v_fmac_f32 %[aa], %[t2], %[e2]\n\t"                                  \
        "v_fmac_f32 %[ab], %[t3], %[e3]\n\t"                                  \
        "v_fmac_f32 %[aa], %[t4], %[e4]\n\t"                                  \
        "v_fmac_f32 %[ab], %[t5], %[e5]\n\t"                                  \
        "v_fmac_f32 %[aa], %[t6], %[e6]\n\t"                                  \
        "v_fmac_f32 %[ab], %[t7], %[e7]\n\t"                                  \
        : [aa] "+v"(AA), [ab] "+v"(AB),                                       \
          [t0] "=&s"(t0_), [t1] "=&s"(t1_), [t2] "=&s"(t2_), [t3] "=&s"(t3_), \
          [t4] "=&s"(t4_), [t5] "=&s"(t5_), [t6] "=&s"(t6_), [t7] "=&s"(t7_)  \
        : [uu] "v"(uu),                                                       \
          [e0] "v"(E[(B)+0]), [e1] "v"(E[(B)+1]), [e2] "v"(E[(B)+2]),         \
          [e3] "v"(E[(B)+3]), [e4] "v"(E[(B)+4]), [e5] "v"(E[(B)+5]),         \
          [e6] "v"(E[(B)+6]), [e7] "v"(E[(B)+7]),                             \
          [l0] "i"((B)+0), [l1] "i"((B)+1), [l2] "i"((B)+2), [l3] "i"((B)+3), \
          [l4] "i"((B)+4), [l5] "i"((B)+5), [l6] "i"((B)+6), [l7] "i"((B)+7));\
  } while (0)

#define BLK6(B, AA, AB)                                                       \
  do {                                                                        \
    int t0_,t1_,t2_,t3_,t4_,t5_;                                              \
    asm("v_readlane_b32 %[t0], %[uu], %[l0]\n\t"                              \
        "v_readlane_b32 %[t1], %[uu], %[l1]\n\t"                              \
        "v_readlane_b32 %[t2], %[uu], %[l2]\n\t"                              \
        "v_readlane_b32 %[t3], %[uu], %[l3]\n\t"                              \
        "v_readlane_b32 %[t4], %[uu], %[l4]\n\t"                              \
        "v_readlane_b32 %[t5], %[uu], %[l5]\n\t"                              \
        "v_fmac_f32 %[aa], %[t0], %[e0]\n\t"                                  \
        "v_fmac_f32 %[ab], %[t1], %[e1]\n\t"                                  \
        "v_fmac_f32 %[aa], %[t2], %[e2]\n\t"                                  \
        "v_fmac_f32 %[ab], %[t3], %[e3]\n\t"                                  \
        "v_fmac_f32 %[aa], %[t4], %[e4]\n\t"                                  \
        "v_fmac_f32 %[ab], %[t5], %[e5]\n\t"                                  \
        : [aa] "+v"(AA), [ab] "+v"(AB),                                       \
          [t0] "=&s"(t0_), [t1] "=&s"(t1_), [t2] "=&s"(t2_),                  \
          [t3] "=&s"(t3_), [t4] "=&s"(t4_), [t5] "=&s"(t5_)                   \
        : [uu] "v"(uu),                                                       \
          [e0] "v"(E[(B)+0]), [e1] "v"(E[(B)+1]), [e2] "v"(E[(B)+2]),         \
          [e3] "v"(E[(B)+3]), [e4] "v"(E[(B)+4]), [e5] "v"(E[(B)+5]),         \
          [l0] "i"((B)+0), [l1] "i"((B)+1), [l2] "i"((B)+2),                  \
          [l3] "i"((B)+3), [l4] "i"((B)+4), [l5] "i"((B)+5));                 \
  } while (0)

__global__ __launch_bounds__(128, 1) void crf_fwd_kernel(
    const float* __restrict__ em, const float* __restrict__ tr,
    const int* __restrict__ tags, const int* __restrict__ mask,
    float* __restrict__ part, int* __restrict__ msum)
{
    __shared__ float tlds[NTAG * NTAG];
    __shared__ __align__(16) float flds[2][32][64];   // ring per wave
    __shared__ float xv[64];                           // backward result
    __shared__ int   xe;                               // backward esum

    const int tid = threadIdx.x;
    for (int k = tid; k < NTAG * NTAG; k += 128) tlds[k] = tr[k];
    __syncthreads();

    const int  wv   = tid >> 6;        // 0 = forward, 1 = backward
    const int  lane = tid & 63;
    const int  b    = blockIdx.x;
    const bool bwd  = (wv == 1);
    const size_t bT = (size_t)b * NTAG;

    // --- E row (fwd) or E column (bwd), exp'd, 54 VGPRs, pinned ---
    float E[NTAG];
    #pragma unroll
    for (int i = 0; i < NTAG; ++i) {
        E[i] = (lane < NTAG)
                 ? __expf(bwd ? tlds[i * NTAG + lane] : tlds[lane * NTAG + i])
                 : 0.f;
        asm("" : "+v"(E[i]));
    }
    float estop = (lane < NTAG) ? __expf(tlds[TSTOP * NTAG + lane]) : 0.f;

    // =======================================================================
    // Prepass: gold + mask ballots
    // =======================================================================
    float    goldp = 0.f;
    int      msump = 0;
    uint64_t B[8];
    #pragma unroll
    for (int r = 0; r < 8; ++r) {
        int s  = r * 64 + lane;
        int tg = tags[s * BATCH + b];
        int mk = mask[s * BATCH + b];
        int tp = (s == 0) ? TSTART : tags[(s - 1) * BATCH + b];
        float emv = em[(size_t)s * EMROW + bT + tg];
        float trv = tlds[tg * NTAG + tp];
        float mf  = (s == 0) ? 1.f : (float)mk;
        goldp = fmaf(trv + emv, mf, goldp);
        msump += mk;
        B[r] = __ballot(mk > 0);
    }
    #pragma unroll
    for (int off = 32; off >= 1; off >>= 1) {
        goldp += __shfl_xor(goldp, off);
        msump += __shfl_xor(msump, off);
    }
    uint64_t Bw[4];
    #pragma unroll
    for (int r = 0; r < 4; ++r)
        Bw[r] = bwd ? __brevll(B[7 - r]) : B[r];

    // =======================================================================
    // 256-step half-chain recursion (per wave)
    // =======================================================================
    float u     = bwd ? estop : ((lane == TSTART) ? 1.f : 0.f);
    int   esum  = 0;
    int   e_lag = 0;

    asm volatile("s_waitcnt vmcnt(0)" ::: "memory");   // drain prepass VMEM

    const float* gbase = em + bT + (lane < NTAG ? lane : NTAG - 1);
    #define ROWOF(ts_) ((unsigned)(bwd ? (511 - (ts_)) : (ts_)))

    #pragma unroll
    for (int s = 0; s < 16; ++s)                        // stage steps 0..15
        stage4(gbase + (size_t)(ROWOF(s) * (unsigned)EMROW),
               (float*)&flds[wv][s][0]);

    for (int ch = 0; ch < 4; ++ch) {
        uint64_t cur = Bw[ch];
        #pragma unroll
        for (int i = 0; i < NTAG; ++i) asm("" : "+v"(E[i]));  // keep VGPR homes
        #pragma unroll 1
        for (int g = 0; g < 8; ++g) {
            const int gb = ch * 64 + g * 8;
            asm volatile("s_waitcnt vmcnt(8)" ::: "memory");
            float ef[8];
            #pragma unroll
            for (int k = 0; k < 8; ++k)
                ef[k] = __expf(flds[wv][(gb + k) & 31][lane]);
            #pragma unroll
            for (int k = 0; k < 8; ++k) {
                int ts = gb + 16 + k;
                ts = ts > 255 ? 255 : ts;               // tail: dummy restage
                stage4(gbase + (size_t)(ROWOF(ts) * (unsigned)EMROW),
                       (float*)&flds[wv][(gb + 16 + k) & 31][0]);
            }
            #pragma unroll
            for (int k = 0; k < 8; ++k) {
                float scl = ef[k] * __uint_as_float((unsigned)(127 - e_lag) << 23);
                float pre = bwd ? u * scl : u;          // bwd scales before E^T
                int uu = __float_as_int(pre);
                float a0 = 0.f, a1 = 0.f, a2 = 0.f, a3 = 0.f;
                BLK8( 0, a0, a1);
                BLK8( 8, a2, a3);
                BLK8(16, a0, a1);
                BLK8(24, a2, a3);
                BLK8(32, a0, a1);
                BLK8(40, a2, a3);
                BLK6(48, a0, a1);
                float w  = (a0 + a2) + (a1 + a3);
                float un = bwd ? w : w * scl;           // fwd scales after E
                bool  up = ((cur & 1ull) != 0ull) && (lane < NTAG);
                u = up ? un : u;
                esum += up ? e_lag : 0;
                cur >>= 1;
                int ub = __builtin_amdgcn_readlane(__float_as_int(u), 0);
                int en = ((ub >> 23) & 255) - 127;
                e_lag = en < -40 ? -40 : (en > 40 ? 40 : en);
            }
        }
    }
    #undef ROWOF

    // =======================================================================
    // Combine halves: w = <u_fwd, v_bwd> * 2^(esumF+esumB)
    // =======================================================================
    if (bwd) {
        xv[lane] = u;
        if (lane == 0) xe = esum;
    }
    __syncthreads();

    if (!bwd) {
        float us = u * xv[lane];
        #pragma unroll
        for (int off = 32; off >= 1; off >>= 1) us += __shfl_xor(us, off);
        float fwd = __logf(us) + (float)(esum + xe) * 0.69314718f;

        asm volatile("s_waitcnt vmcnt(0)" ::: "memory");
        int li   = (msump > 0) ? (msump - 1) : 0;
        int ltag = tags[li * BATCH + b];
        float gold = goldp + tlds[TSTOP * NTAG + ltag];

        if (lane == 0) { part[b] = fwd - gold; msum[b] = msump; }
    }
}

// ---------------------------------------------------------------------------
// Kernel 2: deterministic reduction  out = sum(part) / sum(msum)
// ---------------------------------------------------------------------------
__global__ __launch_bounds__(256) void crf_reduce_kernel(
    const float* __restrict__ part, const int* __restrict__ msum,
    float* __restrict__ out)
{
    const int tid = threadIdx.x;
    float s = 0.f;
    int   m = 0;
    for (int k = tid; k < BATCH; k += 256) { s += part[k]; m += msum[k]; }
    #pragma unroll
    for (int off = 32; off >= 1; off >>= 1) {
        s += __shfl_xor(s, off);
        m += __shfl_xor(m, off);
    }
    __shared__ float sl[4];
    __shared__ int   ml[4];
    if ((tid & 63) == 0) { sl[tid >> 6] = s; ml[tid >> 6] = m; }
    __syncthreads();
    if (tid == 0)
        out[0] = (sl[0] + sl[1] + sl[2] + sl[3]) /
                 (float)(ml[0] + ml[1] + ml[2] + ml[3]);
}

extern "C" void kernel_launch(void* const* d_in, const int* in_sizes, int n_in,
                              void* d_out, int out_size, void* d_ws, size_t ws_size,
                              hipStream_t stream)
{
    const float* em   = (const float*)d_in[0];
    const float* tr   = (const float*)d_in[1];
    const int*   tags = (const int*)d_in[2];
    const int*   mask = (const int*)d_in[3];

    float* part  = (float*)d_ws;
    int*   msumw = (int*)((char*)d_ws + BATCH * sizeof(float));
    float* out   = (float*)d_out;

    crf_fwd_kernel<<<BATCH, 128, 0, stream>>>(em, tr, tags, mask, part, msumw);
    crf_reduce_kernel<<<1, 256, 0, stream>>>(part, msumw, out);
}